// Round 2
// baseline (7639.939 us; speedup 1.0000x reference)
//
#include <hip/hip_runtime.h>

#define Bn   32
#define Cn   64
#define Ln   4096
#define Nn   (Bn*Cn*Ln)      // 8388608
#define FLn  8
#define MIDn 16
#define TILE  64
#define TILE3 64

__device__ __forceinline__ float gelu_f(float x) {
    return 0.5f * x * (1.0f + erff(x * 0.7071067811865476f));
}
__device__ __forceinline__ float sigmoid_f(float x) {
    return 1.0f / (1.0f + __expf(-x));
}

// ---------------- weight transposes: [(oc,c,k)] -> [(c*3+k)*64 + oc] ----------------
__global__ __launch_bounds__(256) void transpose_weights(
    const float* __restrict__ w1, const float* __restrict__ w2,
    const float* __restrict__ gw, const float* __restrict__ aw2,
    float* __restrict__ w1t, float* __restrict__ w2t,
    float* __restrict__ gwt, float* __restrict__ aw2t)
{
    int idx = blockIdx.x*256 + threadIdx.x;
    if (idx < 64*192) {
        int oc = idx / 192, r = idx % 192;
        w1t[r*64 + oc] = w1[idx];
        w2t[r*64 + oc] = w2[idx];
    }
    if (idx < 3*64*192) {
        int lvl = idx / 12288, rem = idx % 12288;
        int oc = rem / 192, r = rem % 192;
        gwt[lvl*12288 + r*64 + oc] = gw[idx];
    }
    if (idx < 2*64*16) {
        int lvl = idx / 1024, rem = idx % 1024;
        int oc = rem / 16, mm = rem % 16;
        aw2t[lvl*1024 + mm*64 + oc] = aw2[idx];
    }
}

// ---------------- fused ODE f-eval + RK4 stage update ----------------
// k = tanh(conv2(gelu(conv1(zin)))) - damp*zin  (both convs k=3, edge pad)
// NOTE: reference edge-pads the INTERMEDIATE h before conv2, i.e. h[-1]:=h[0],
// h[L]:=h[L-1]. We fix up the halo columns of h1_s on boundary tiles.
// stage 0: acc = k;     znext = zbase + 0.05*k
// stage 1: acc += 2k;   znext = zbase + 0.05*k
// stage 2: acc += 2k;   znext = zbase + 0.1*k
// stage 3: znext = zbase + (0.1/6)*(acc + k)
__global__ __launch_bounds__(256) void ode_f_kernel(
    const float* __restrict__ zin, const float* __restrict__ zbase,
    float* __restrict__ acc, float* __restrict__ znext,
    const float* __restrict__ w1t, const float* __restrict__ b1,
    const float* __restrict__ w2t, const float* __restrict__ b2,
    const float* __restrict__ damp_p, int stage)
{
    __shared__ float zin_s[Cn][TILE+4];   // cols j: l = l0-2+j (edge-clamped)
    __shared__ float h1_s[Cn][TILE+2];    // cols i: l = l0-1+i
    const int b  = blockIdx.y;
    const int l0 = blockIdx.x * TILE;
    const int tid = threadIdx.x;
    const float* __restrict__ zb = zin + (size_t)b*Cn*Ln;

    for (int idx = tid; idx < Cn*(TILE+4); idx += 256) {
        int c = idx / (TILE+4);
        int j = idx - c*(TILE+4);
        int l = l0 - 2 + j;
        l = l < 0 ? 0 : (l > Ln-1 ? Ln-1 : l);
        zin_s[c][j] = zb[c*Ln + l];
    }
    __syncthreads();

    const int oc = tid & 63;
    const int pg = tid >> 6;

    // conv1 -> gelu -> h1_s : positions i in [0, TILE+2)
    {
        const int i0 = pg*17;
        const int np = min(17, (TILE+2) - i0);   // 17,17,17,15
        float a[17];
        const float bb = b1[oc];
        #pragma unroll
        for (int j = 0; j < 17; ++j) a[j] = bb;
        for (int c = 0; c < Cn; ++c) {
            const float* zr = &zin_s[c][i0];
            const float w0 = w1t[(c*3+0)*64 + oc];
            const float w1 = w1t[(c*3+1)*64 + oc];
            const float w2 = w1t[(c*3+2)*64 + oc];
            float x0 = zr[0], x1 = zr[1];
            #pragma unroll
            for (int j = 0; j < 17; ++j) {
                if (j < np) {
                    float x2 = zr[j+2];
                    a[j] = fmaf(w0, x0, fmaf(w1, x1, fmaf(w2, x2, a[j])));
                    x0 = x1; x1 = x2;
                }
            }
        }
        for (int j = 0; j < np; ++j) h1_s[oc][i0+j] = gelu_f(a[j]);
    }
    __syncthreads();

    // edge-pad fixup of h (reference pads h itself, not recompute):
    //   first tile: h(l=-1) := h(l=0) ; last tile: h(l=L) := h(l=L-1)
    if (blockIdx.x == 0 && tid < Cn)            h1_s[tid][0]      = h1_s[tid][1];
    if (blockIdx.x == gridDim.x-1 && tid < Cn)  h1_s[tid][TILE+1] = h1_s[tid][TILE];
    __syncthreads();

    // conv2 -> tanh -> -damp*zin : positions t in [0, TILE)
    float kv[16];
    const int t0 = pg*16;
    {
        const float bb = b2[oc];
        #pragma unroll
        for (int j = 0; j < 16; ++j) kv[j] = bb;
        for (int c = 0; c < Cn; ++c) {
            const float* hr = &h1_s[c][t0];
            const float w0 = w2t[(c*3+0)*64 + oc];
            const float w1 = w2t[(c*3+1)*64 + oc];
            const float w2 = w2t[(c*3+2)*64 + oc];
            float x0 = hr[0], x1 = hr[1];
            #pragma unroll
            for (int j = 0; j < 16; ++j) {
                float x2 = hr[j+2];
                kv[j] = fmaf(w0, x0, fmaf(w1, x1, fmaf(w2, x2, kv[j])));
                x0 = x1; x1 = x2;
            }
        }
        const float damp = damp_p[0];
        #pragma unroll
        for (int j = 0; j < 16; ++j)
            kv[j] = tanhf(kv[j]) - damp * zin_s[oc][t0 + j + 2];
    }
    __syncthreads();
    #pragma unroll
    for (int j = 0; j < 16; ++j) zin_s[oc][t0 + j] = kv[j];   // reuse zin_s for k
    __syncthreads();

    const size_t gb0 = (size_t)b*Cn*Ln + l0;
    for (int e = tid; e < Cn*TILE; e += 256) {
        int c = e >> 6;
        int t = e & 63;
        size_t g = gb0 + (size_t)c*Ln + t;
        float k = zin_s[c][t];
        if (stage == 0)      { acc[g] = k;        znext[g] = zbase[g] + 0.05f*k; }
        else if (stage == 1) { acc[g] += 2.0f*k;  znext[g] = zbase[g] + 0.05f*k; }
        else if (stage == 2) { acc[g] += 2.0f*k;  znext[g] = zbase[g] + 0.1f*k;  }
        else                 { znext[g] = zbase[g] + (0.1f/6.0f)*(acc[g] + k);   }
    }
}

// ---------------- per-row mean over L ----------------
__global__ __launch_bounds__(256) void mean_kernel(const float* __restrict__ in, float* __restrict__ m)
{
    const int bc = blockIdx.x;
    const float* __restrict__ row = in + (size_t)bc*Ln;
    float s = 0.0f;
    for (int l = threadIdx.x; l < Ln; l += 256) s += row[l];
    #pragma unroll
    for (int off = 32; off > 0; off >>= 1) s += __shfl_down(s, off, 64);
    __shared__ float red[4];
    if ((threadIdx.x & 63) == 0) red[threadIdx.x >> 6] = s;
    __syncthreads();
    if (threadIdx.x == 0) m[bc] = (red[0]+red[1]+red[2]+red[3]) * (1.0f/Ln);
}

// ---------------- dywan: tiny MLP -> lo/hi + ortho contribution ----------------
__global__ __launch_bounds__(256) void dywan_kernel(
    const float* __restrict__ m,
    const float* __restrict__ stat_w, const float* __restrict__ stat_b,
    const float* __restrict__ gen1_w, const float* __restrict__ gen1_b,
    const float* __restrict__ gen2_w, const float* __restrict__ gen2_b,
    float* __restrict__ tail, int lvl)
{
    __shared__ float m_s[Bn][Cn];
    __shared__ float stat_s[Bn][64];
    __shared__ float g1_s[Bn][128];
    __shared__ float g_s[Bn][16];
    __shared__ float ored[Bn];
    const int tid = threadIdx.x;
    for (int i = tid; i < Bn*Cn; i += 256) m_s[i>>6][i&63] = m[i];
    __syncthreads();
    for (int i = tid; i < Bn*64; i += 256) {
        int b = i >> 6, h = i & 63;
        float a = stat_b[h];
        for (int c = 0; c < Cn; ++c) a = fmaf(stat_w[h*64+c], m_s[b][c], a);
        stat_s[b][h] = gelu_f(a);
    }
    __syncthreads();
    for (int i = tid; i < Bn*128; i += 256) {
        int b = i >> 7, j = i & 127;
        float a = gen1_b[j];
        for (int h = 0; h < 64; ++h) a = fmaf(gen1_w[j*64+h], stat_s[b][h], a);
        g1_s[b][j] = gelu_f(a);
    }
    __syncthreads();
    for (int i = tid; i < Bn*16; i += 256) {
        int b = i >> 4, q = i & 15;
        float a = gen2_b[q];
        for (int j = 0; j < 128; ++j) a = fmaf(gen2_w[q*128+j], g1_s[b][j], a);
        g_s[b][q] = a;
    }
    __syncthreads();
    // write lo (q<8) and hi (q>=8) to d_out tail: [ortho][los(3,32,8)][his(3,32,8)]
    for (int i = tid; i < Bn*16; i += 256) {
        int b = i >> 4, q = i & 15;
        if (q < FLn) tail[1 + lvl*(Bn*FLn) + b*FLn + q] = g_s[b][q];
        else         tail[1 + 3*(Bn*FLn) + lvl*(Bn*FLn) + b*FLn + (q-FLn)] = g_s[b][q];
    }
    if (tid < Bn) {
        const int b = tid;
        float S1 = 0.f, n2 = 0.f, sm = 0.f, prev = 0.f;
        #pragma unroll
        for (int k = 0; k < FLn; ++k) {
            float v = g_s[b][k];
            S1 += fabsf(v); n2 = fmaf(v, v, n2);
            sm += fabsf(v - prev); prev = v;
        }
        sm += fabsf(prev);                       // trailing pad diff
        float den = sqrtf(n2) + 1e-8f;
        float Sn = S1 / den;
        float s2n = n2 / (den*den);
        // shift = 3 * mean_b(Sn^2)/64 ; amp = mean_b|s2n-1| ; smooth = mean(B*9)
        ored[b] = 0.01f * (3.0f*Sn*Sn*(1.0f/2048.0f) + fabsf(s2n - 1.0f)*(1.0f/32.0f))
                + 0.1f * sm * (1.0f/288.0f);
    }
    __syncthreads();
    if (tid == 0) {
        float o = 0.f;
        for (int b = 0; b < Bn; ++b) o += ored[b];
        if (lvl == 0) tail[0] = o; else tail[0] += o;
    }
}

// ---------------- per-batch 8-tap FIR (lo -> new approx, hi -> details) ----------------
__global__ __launch_bounds__(256) void filter_kernel(
    const float* __restrict__ in, float* __restrict__ napprox,
    float* __restrict__ det,
    const float* __restrict__ lo, const float* __restrict__ hi)
{
    const int bc = blockIdx.y;
    const int b = bc >> 6;
    float lov[8], hiv[8];
    #pragma unroll
    for (int k = 0; k < 8; ++k) { lov[k] = lo[b*8+k]; hiv[k] = hi[b*8+k]; }
    const float* __restrict__ row = in + (size_t)bc*Ln;
    const int l = blockIdx.x*256 + threadIdx.x;
    float na = 0.0f, dv = 0.0f;
    #pragma unroll
    for (int k = 0; k < 8; ++k) {
        int j = l + k - 4;
        j = j < 0 ? 0 : (j >= Ln ? Ln-1 : j);   // edge pad
        float v = row[j];
        na = fmaf(v, lov[k], na);
        dv = fmaf(v, hiv[k], dv);
    }
    size_t g = (size_t)bc*Ln + l;
    if (napprox) napprox[g] = na;
    det[g] = dv;
}

// ---------------- reconstruction: att(1x1 convs) + gate(3-conv, zero pad) + updates ----------------
template<bool HAS_ATT>
__global__ __launch_bounds__(256) void stage3_kernel(
    const float* __restrict__ cur_in, float* __restrict__ det,
    float* __restrict__ cur_out,
    const float* __restrict__ gwt, const float* __restrict__ gb,
    const float* __restrict__ aw1, const float* __restrict__ ab1,
    const float* __restrict__ aw2t, const float* __restrict__ ab2)
{
    __shared__ float cur_s[Cn][TILE3+2];
    __shared__ float t1_s[MIDn][TILE3];
    __shared__ float gate_s[Cn][TILE3];
    __shared__ float att_s[Cn][TILE3];
    const int b  = blockIdx.y;
    const int l0 = blockIdx.x * TILE3;
    const int tid = threadIdx.x;
    const float* __restrict__ cb = cur_in + (size_t)b*Cn*Ln;

    for (int idx = tid; idx < Cn*(TILE3+2); idx += 256) {
        int c = idx / (TILE3+2);
        int j = idx - c*(TILE3+2);
        int l = l0 - 1 + j;
        cur_s[c][j] = (l < 0 || l >= Ln) ? 0.0f : cb[c*Ln + l];   // zero pad
    }
    __syncthreads();

    if (HAS_ATT) {
        for (int i = tid; i < MIDn*TILE3; i += 256) {
            int mm = i / TILE3, t = i - mm*TILE3;
            float a = ab1[mm];
            for (int c = 0; c < Cn; ++c) a = fmaf(aw1[mm*64 + c], cur_s[c][t+1], a);
            t1_s[mm][t] = gelu_f(a);
        }
        __syncthreads();
    }

    const int oc = tid & 63;
    const int pg = tid >> 6;
    const int t0 = pg*16;
    {
        float gv[16];
        const float bb = gb[oc];
        #pragma unroll
        for (int j = 0; j < 16; ++j) gv[j] = bb;
        for (int c = 0; c < Cn; ++c) {
            const float* cr = &cur_s[c][t0];
            const float w0 = gwt[(c*3+0)*64 + oc];
            const float w1 = gwt[(c*3+1)*64 + oc];
            const float w2 = gwt[(c*3+2)*64 + oc];
            float x0 = cr[0], x1 = cr[1];
            #pragma unroll
            for (int j = 0; j < 16; ++j) {
                float x2 = cr[j+2];
                gv[j] = fmaf(w0, x0, fmaf(w1, x1, fmaf(w2, x2, gv[j])));
                x0 = x1; x1 = x2;
            }
        }
        #pragma unroll
        for (int j = 0; j < 16; ++j) gate_s[oc][t0+j] = sigmoid_f(gv[j]);
    }
    if (HAS_ATT) {
        float av[16];
        const float bb = ab2[oc];
        #pragma unroll
        for (int j = 0; j < 16; ++j) av[j] = bb;
        for (int mm = 0; mm < MIDn; ++mm) {
            const float w = aw2t[mm*64 + oc];
            #pragma unroll
            for (int j = 0; j < 16; ++j) av[j] = fmaf(w, t1_s[mm][t0+j], av[j]);
        }
        #pragma unroll
        for (int j = 0; j < 16; ++j) att_s[oc][t0+j] = sigmoid_f(av[j]);
    }
    __syncthreads();

    const size_t gb0 = (size_t)b*Cn*Ln + l0;
    for (int e = tid; e < Cn*TILE3; e += 256) {
        int c = e >> 6, t = e & 63;
        size_t g = gb0 + (size_t)c*Ln + t;
        float d = det[g];
        if (HAS_ATT) { d = d * (1.0f + att_s[c][t]); det[g] = d; }
        cur_out[g] = cur_s[c][t+1] + gate_s[c][t]*d;
    }
}

extern "C" void kernel_launch(void* const* d_in, const int* in_sizes, int n_in,
                              void* d_out, int out_size, void* d_ws, size_t ws_size,
                              hipStream_t stream)
{
    const float* x      = (const float*)d_in[0];
    const float* c1w    = (const float*)d_in[1];
    const float* c1b    = (const float*)d_in[2];
    const float* c2w    = (const float*)d_in[3];
    const float* c2b    = (const float*)d_in[4];
    const float* damp   = (const float*)d_in[5];
    const float* stat_w = (const float*)d_in[6];
    const float* stat_b = (const float*)d_in[7];
    const float* gen1_w = (const float*)d_in[8];
    const float* gen1_b = (const float*)d_in[9];
    const float* gen2_w = (const float*)d_in[10];
    const float* gen2_b = (const float*)d_in[11];
    const float* gate_w = (const float*)d_in[12];
    const float* gate_b = (const float*)d_in[13];
    const float* att_w1 = (const float*)d_in[14];
    const float* att_b1 = (const float*)d_in[15];
    const float* att_w2 = (const float*)d_in[16];
    const float* att_b2 = (const float*)d_in[17];

    float* out = (float*)d_out;
    // workspace layout: [Z (N)] [WSB (N)] [small: w1t w2t gwt aw2t m_ws]
    float* Z    = (float*)d_ws;
    float* WSB  = Z + Nn;
    float* SM   = WSB + Nn;
    float* w1t  = SM;
    float* w2t  = w1t + 12288;
    float* gwt  = w2t + 12288;
    float* aw2t = gwt + 36864;
    float* m_ws = aw2t + 2048;

    // RK4 scratch borrows d_out's enhanced slots (free until stage 2)
    float* ACC  = out + (size_t)3*Nn;
    float* ZINA = out + (size_t)1*Nn;
    float* ZINB = out + (size_t)2*Nn;
    float* tail = out + (size_t)4*Nn;

    hipMemcpyAsync(Z, x, (size_t)Nn*sizeof(float), hipMemcpyDeviceToDevice, stream);
    transpose_weights<<<144, 256, 0, stream>>>(c1w, c2w, gate_w, att_w2, w1t, w2t, gwt, aw2t);

    dim3 gOde(Ln/TILE, Bn);
    for (int s = 0; s < 10; ++s) {
        ode_f_kernel<<<gOde, 256, 0, stream>>>(Z,    Z, ACC, ZINA, w1t, c1b, w2t, c2b, damp, 0);
        ode_f_kernel<<<gOde, 256, 0, stream>>>(ZINA, Z, ACC, ZINB, w1t, c1b, w2t, c2b, damp, 1);
        ode_f_kernel<<<gOde, 256, 0, stream>>>(ZINB, Z, ACC, ZINA, w1t, c1b, w2t, c2b, damp, 2);
        ode_f_kernel<<<gOde, 256, 0, stream>>>(ZINA, Z, ACC, Z,    w1t, c1b, w2t, c2b, damp, 3);
    }

    // stage 2: wavelet levels. approx chain: Z -> WSB -> out(cur slot) -> (dropped)
    dim3 gFil(Ln/256, Bn*Cn);
    const float* appr_in[3] = {Z, WSB, out};
    float*       appr_out[3] = {WSB, out, nullptr};
    for (int lvl = 0; lvl < 3; ++lvl) {
        mean_kernel<<<Bn*Cn, 256, 0, stream>>>(appr_in[lvl], m_ws);
        dywan_kernel<<<1, 256, 0, stream>>>(m_ws, stat_w, stat_b, gen1_w, gen1_b,
                                            gen2_w, gen2_b, tail, lvl);
        filter_kernel<<<gFil, 256, 0, stream>>>(appr_in[lvl], appr_out[lvl],
            out + (size_t)(1+lvl)*Nn,
            tail + 1 + lvl*(Bn*FLn),
            tail + 1 + 3*(Bn*FLn) + lvl*(Bn*FLn));
    }

    // stage 3: reconstruction. cur chain: Z -> WSB -> Z -> out (final)
    dim3 gS3(Ln/TILE3, Bn);
    stage3_kernel<false><<<gS3, 256, 0, stream>>>(Z, out + (size_t)3*Nn, WSB,
        gwt + 2*12288, gate_b + 2*64, nullptr, nullptr, nullptr, nullptr);
    stage3_kernel<true><<<gS3, 256, 0, stream>>>(WSB, out + (size_t)2*Nn, Z,
        gwt + 1*12288, gate_b + 1*64, att_w1 + 1024, att_b1 + 16, aw2t + 1024, att_b2 + 64);
    stage3_kernel<true><<<gS3, 256, 0, stream>>>(Z, out + (size_t)1*Nn, out,
        gwt, gate_b, att_w1, att_b1, aw2t, att_b2);
}

// Round 3
// 2667.738 us; speedup vs baseline: 2.8638x; 2.8638x over previous
//
#include <hip/hip_runtime.h>

#define Bn   32
#define Cn   64
#define Ln   4096
#define Nn   (Bn*Cn*Ln)      // 8388608
#define FLn  8
#define MIDn 16
#define TILE3 64
#define NT   128             // ODE output positions per block

typedef __bf16 bf16_t;
typedef bf16_t bf16x4 __attribute__((ext_vector_type(4)));
typedef bf16_t bf16x8 __attribute__((ext_vector_type(8)));
typedef float  f32x16 __attribute__((ext_vector_type(16)));

__device__ __forceinline__ float gelu_f(float x) {
    return 0.5f * x * (1.0f + erff(x * 0.7071067811865476f));
}
__device__ __forceinline__ float sigmoid_f(float x) {
    return 1.0f / (1.0f + __expf(-x));
}

// swizzled LDS element index (pitch 64 bf16 = 128B rows, 8B-granule XOR)
__device__ __forceinline__ int zel(int p, int c) { return p*64 + (c ^ ((p & 15) << 2)); }

// ---------------- weight prep: MFMA A-frags + gate/att transposes ----------------
// A-frag order for mfma_f32_32x32x16_bf16: lane l holds A[row=l&31][k=(l>>5)*8+e]
// frag f = tau*4 + ks  (tap tau, K-chunk ks of 16); entry (mt, f, lane) -> 8 bf16.
__global__ __launch_bounds__(256) void prep_weights(
    const float* __restrict__ w1, const float* __restrict__ w2,
    const float* __restrict__ gw, const float* __restrict__ aw2,
    bf16_t* __restrict__ w1f, bf16_t* __restrict__ w2f,
    float* __restrict__ gwt, float* __restrict__ aw2t)
{
    int idx = blockIdx.x*256 + threadIdx.x;
    if (idx < 1536) {
        int lane = idx & 63;
        int f  = (idx >> 6) % 12;
        int mt = (idx >> 6) / 12;
        int tau = f >> 2, ks = f & 3;
        int oc = mt*32 + (lane & 31);
        int c0 = ks*16 + (lane >> 5)*8;
        #pragma unroll
        for (int e = 0; e < 8; ++e) {
            int c = c0 + e;
            w1f[idx*8 + e] = (bf16_t)w1[oc*192 + c*3 + tau];
            w2f[idx*8 + e] = (bf16_t)w2[oc*192 + c*3 + tau];
        }
    }
    if (idx < 3*64*192) {
        int lvl = idx / 12288, rem = idx % 12288;
        int oc = rem / 192, r = rem % 192;
        gwt[lvl*12288 + r*64 + oc] = gw[idx];
    }
    if (idx < 2*64*16) {
        int lvl = idx / 1024, rem = idx % 1024;
        int oc = rem / 16, mm = rem % 16;
        aw2t[lvl*1024 + mm*64 + oc] = aw2[idx];
    }
}

// ---------------- MFMA ODE f-eval + RK4 stage update ----------------
// k = tanh(conv2(gelu(conv1(zin)))) - damp*zin  (k=3 convs, edge pad; the
// INTERMEDIATE h is edge-padded per reference -> boundary row fixups).
// STAGE 0: znext = zb + 0.05*k          (zb == zin)
// STAGE 1: znext = zb + 0.05*k
// STAGE 2: znext = zb + 0.1*k
// STAGE 3: znext = (xA + 2*xB + zin - zb)/3 + k/60   (acc-free RK4 combine)
template<int STAGE>
__global__ __launch_bounds__(256) void ode_mfma(
    const float* __restrict__ zin, const float* __restrict__ zb,
    const float* __restrict__ xA, const float* __restrict__ xB,
    float* __restrict__ znext,
    const bf16_t* __restrict__ w1f, const float* __restrict__ b1,
    const bf16_t* __restrict__ w2f, const float* __restrict__ b2,
    const float* __restrict__ damp_p)
{
    __shared__ bf16_t ztb[168*64];   // z tile, rows p: l = l0-3+p (clamped), 21.5KB
    __shared__ bf16_t htb[136*64];   // h tile, rows q: h at l0-1+q,          17.4KB

    const int tid  = threadIdx.x;
    const int w    = tid >> 6;
    const int lane = tid & 63;
    const int n31  = lane & 31;
    const int g    = lane >> 5;
    const int mt   = w & 1;
    const int b    = blockIdx.y;
    const int l0   = blockIdx.x * NT;
    const size_t bbase = (size_t)b * Cn * Ln;
    const float damp = damp_p[0];

    // ---- stage zin -> ztb (bf16, transposed, swizzled) ----
    for (int cc = 0; cc < 16; ++cc) {
        int c = (w << 4) + cc;
        const float* zr = zin + bbase + (size_t)c * Ln;
        #pragma unroll
        for (int m = 0; m < 3; ++m) {
            int p = lane + (m << 6);
            if (p < 168) {
                int l = l0 - 3 + p;
                l = l < 0 ? 0 : (l > Ln-1 ? Ln-1 : l);
                ztb[zel(p, c)] = (bf16_t)zr[l];
            }
        }
    }

    // ---- load conv1 A-frags + biases ----
    bf16x8 af[12];
    {
        const bf16x8* wp = (const bf16x8*)w1f + (mt*12)*64 + lane;
        #pragma unroll
        for (int f = 0; f < 12; ++f) af[f] = wp[f*64];
    }
    float bias1[16];
    #pragma unroll
    for (int r = 0; r < 16; ++r)
        bias1[r] = b1[mt*32 + (r&3) + 8*(r>>2) + 4*g];

    __syncthreads();

    // ---- conv1 -> gelu -> htb : 10 units (2 mt x 5 nt), wave does u=w,w+4,w+8 ----
    for (int u = w; u < 10; u += 4) {
        int nt = u >> 1;
        f32x16 acc = (f32x16)0.0f;
        #pragma unroll
        for (int tau = 0; tau < 3; ++tau) {
            int p  = nt*32 + n31 + tau + 1;
            int pr = p*64, sw = (p & 15) << 2;
            #pragma unroll
            for (int ks = 0; ks < 4; ++ks) {
                int c0 = ks*16 + g*8;
                bf16x4 lo = *(const bf16x4*)&ztb[pr + ((c0    ) ^ sw)];
                bf16x4 hi = *(const bf16x4*)&ztb[pr + ((c0 + 4) ^ sw)];
                bf16x8 bb = __builtin_shufflevector(lo, hi, 0,1,2,3,4,5,6,7);
                acc = __builtin_amdgcn_mfma_f32_32x32x16_bf16(af[tau*4+ks], bb, acc, 0, 0, 0);
            }
        }
        int q = nt*32 + n31;       // h row index (h at global l0-1+q)
        if (q < 131) {
            int qr = q*64, qs = (q & 15) << 2;
            #pragma unroll
            for (int t = 0; t < 4; ++t) {
                bf16x4 hv;
                #pragma unroll
                for (int e = 0; e < 4; ++e)
                    hv[e] = (bf16_t)gelu_f(acc[t*4+e] + bias1[t*4+e]);
                int oc0 = mt*32 + t*8 + g*4;
                *(bf16x4*)&htb[qr + (oc0 ^ qs)] = hv;
            }
        }
    }

    __syncthreads();
    // reference edge-pads h itself: h[-1]:=h[0], h[L]:=h[L-1]
    if (blockIdx.x == 0  && tid < 64) htb[zel(0,   tid)] = htb[zel(1,   tid)];
    if (blockIdx.x == 31 && tid < 64) htb[zel(129, tid)] = htb[zel(128, tid)];
    __syncthreads();

    // ---- load conv2 A-frags + biases (reuse regs) ----
    {
        const bf16x8* wp = (const bf16x8*)w2f + (mt*12)*64 + lane;
        #pragma unroll
        for (int f = 0; f < 12; ++f) af[f] = wp[f*64];
    }
    float bias2[16];
    #pragma unroll
    for (int r = 0; r < 16; ++r)
        bias2[r] = b2[mt*32 + (r&3) + 8*(r>>2) + 4*g];

    // ---- conv2 -> tanh -> damp -> RK4 epilogue : 8 units ----
    for (int u = w; u < 8; u += 4) {
        int nt = u >> 1;
        f32x16 acc = (f32x16)0.0f;
        #pragma unroll
        for (int tau = 0; tau < 3; ++tau) {
            int q  = nt*32 + n31 + tau;
            int qr = q*64, qs = (q & 15) << 2;
            #pragma unroll
            for (int ks = 0; ks < 4; ++ks) {
                int c0 = ks*16 + g*8;
                bf16x4 lo = *(const bf16x4*)&htb[qr + ((c0    ) ^ qs)];
                bf16x4 hi = *(const bf16x4*)&htb[qr + ((c0 + 4) ^ qs)];
                bf16x8 bb = __builtin_shufflevector(lo, hi, 0,1,2,3,4,5,6,7);
                acc = __builtin_amdgcn_mfma_f32_32x32x16_bf16(af[tau*4+ks], bb, acc, 0, 0, 0);
            }
        }
        int j = nt*32 + n31;            // output position within tile
        int gcol = l0 + j;
        #pragma unroll
        for (int r = 0; r < 16; ++r) {
            int oc = mt*32 + (r&3) + 8*(r>>2) + 4*g;
            size_t gof = bbase + (size_t)oc * Ln + gcol;
            float zbv = zb[gof];
            float zdv;
            if (STAGE == 0)      zdv = zbv;                       // zin == zb
            else if (STAGE == 3) zdv = zin[gof];                  // fp32 zC
            else                 zdv = (float)ztb[zel(j+3, oc)];  // bf16 zin ok for damp
            float k = tanhf(acc[r] + bias2[r]) - damp * zdv;
            float outv;
            if (STAGE == 0 || STAGE == 1) outv = zbv + 0.05f * k;
            else if (STAGE == 2)          outv = zbv + 0.1f * k;
            else {
                float xav = xA[gof], xbv = xB[gof];
                outv = (xav + 2.0f*xbv + zdv - zbv) * (1.0f/3.0f) + k * (1.0f/60.0f);
            }
            znext[gof] = outv;
        }
    }
}

// ---------------- per-row mean over L ----------------
__global__ __launch_bounds__(256) void mean_kernel(const float* __restrict__ in, float* __restrict__ m)
{
    const int bc = blockIdx.x;
    const float* __restrict__ row = in + (size_t)bc*Ln;
    float s = 0.0f;
    for (int l = threadIdx.x; l < Ln; l += 256) s += row[l];
    #pragma unroll
    for (int off = 32; off > 0; off >>= 1) s += __shfl_down(s, off, 64);
    __shared__ float red[4];
    if ((threadIdx.x & 63) == 0) red[threadIdx.x >> 6] = s;
    __syncthreads();
    if (threadIdx.x == 0) m[bc] = (red[0]+red[1]+red[2]+red[3]) * (1.0f/Ln);
}

// ---------------- dywan: tiny MLP -> lo/hi + ortho contribution ----------------
__global__ __launch_bounds__(256) void dywan_kernel(
    const float* __restrict__ m,
    const float* __restrict__ stat_w, const float* __restrict__ stat_b,
    const float* __restrict__ gen1_w, const float* __restrict__ gen1_b,
    const float* __restrict__ gen2_w, const float* __restrict__ gen2_b,
    float* __restrict__ tail, int lvl)
{
    __shared__ float m_s[Bn][Cn];
    __shared__ float stat_s[Bn][64];
    __shared__ float g1_s[Bn][128];
    __shared__ float g_s[Bn][16];
    __shared__ float ored[Bn];
    const int tid = threadIdx.x;
    for (int i = tid; i < Bn*Cn; i += 256) m_s[i>>6][i&63] = m[i];
    __syncthreads();
    for (int i = tid; i < Bn*64; i += 256) {
        int b = i >> 6, h = i & 63;
        float a = stat_b[h];
        for (int c = 0; c < Cn; ++c) a = fmaf(stat_w[h*64+c], m_s[b][c], a);
        stat_s[b][h] = gelu_f(a);
    }
    __syncthreads();
    for (int i = tid; i < Bn*128; i += 256) {
        int b = i >> 7, j = i & 127;
        float a = gen1_b[j];
        for (int h = 0; h < 64; ++h) a = fmaf(gen1_w[j*64+h], stat_s[b][h], a);
        g1_s[b][j] = gelu_f(a);
    }
    __syncthreads();
    for (int i = tid; i < Bn*16; i += 256) {
        int b = i >> 4, q = i & 15;
        float a = gen2_b[q];
        for (int j = 0; j < 128; ++j) a = fmaf(gen2_w[q*128+j], g1_s[b][j], a);
        g_s[b][q] = a;
    }
    __syncthreads();
    for (int i = tid; i < Bn*16; i += 256) {
        int b = i >> 4, q = i & 15;
        if (q < FLn) tail[1 + lvl*(Bn*FLn) + b*FLn + q] = g_s[b][q];
        else         tail[1 + 3*(Bn*FLn) + lvl*(Bn*FLn) + b*FLn + (q-FLn)] = g_s[b][q];
    }
    if (tid < Bn) {
        const int b = tid;
        float S1 = 0.f, n2 = 0.f, sm = 0.f, prev = 0.f;
        #pragma unroll
        for (int k = 0; k < FLn; ++k) {
            float v = g_s[b][k];
            S1 += fabsf(v); n2 = fmaf(v, v, n2);
            sm += fabsf(v - prev); prev = v;
        }
        sm += fabsf(prev);
        float den = sqrtf(n2) + 1e-8f;
        float Sn = S1 / den;
        float s2n = n2 / (den*den);
        ored[b] = 0.01f * (3.0f*Sn*Sn*(1.0f/2048.0f) + fabsf(s2n - 1.0f)*(1.0f/32.0f))
                + 0.1f * sm * (1.0f/288.0f);
    }
    __syncthreads();
    if (tid == 0) {
        float o = 0.f;
        for (int b = 0; b < Bn; ++b) o += ored[b];
        if (lvl == 0) tail[0] = o; else tail[0] += o;
    }
}

// ---------------- per-batch 8-tap FIR (lo -> new approx, hi -> details) ----------------
__global__ __launch_bounds__(256) void filter_kernel(
    const float* __restrict__ in, float* __restrict__ napprox,
    float* __restrict__ det,
    const float* __restrict__ lo, const float* __restrict__ hi)
{
    const int bc = blockIdx.y;
    const int b = bc >> 6;
    float lov[8], hiv[8];
    #pragma unroll
    for (int k = 0; k < 8; ++k) { lov[k] = lo[b*8+k]; hiv[k] = hi[b*8+k]; }
    const float* __restrict__ row = in + (size_t)bc*Ln;
    const int l = blockIdx.x*256 + threadIdx.x;
    float na = 0.0f, dv = 0.0f;
    #pragma unroll
    for (int k = 0; k < 8; ++k) {
        int j = l + k - 4;
        j = j < 0 ? 0 : (j >= Ln ? Ln-1 : j);
        float v = row[j];
        na = fmaf(v, lov[k], na);
        dv = fmaf(v, hiv[k], dv);
    }
    size_t g = (size_t)bc*Ln + l;
    if (napprox) napprox[g] = na;
    det[g] = dv;
}

// ---------------- reconstruction: att(1x1) + gate(3-conv, zero pad) + updates ----------------
template<bool HAS_ATT>
__global__ __launch_bounds__(256) void stage3_kernel(
    const float* __restrict__ cur_in, float* __restrict__ det,
    float* __restrict__ cur_out,
    const float* __restrict__ gwt, const float* __restrict__ gb,
    const float* __restrict__ aw1, const float* __restrict__ ab1,
    const float* __restrict__ aw2t, const float* __restrict__ ab2)
{
    __shared__ float cur_s[Cn][TILE3+2];
    __shared__ float t1_s[MIDn][TILE3];
    __shared__ float gate_s[Cn][TILE3];
    __shared__ float att_s[Cn][TILE3];
    const int b  = blockIdx.y;
    const int l0 = blockIdx.x * TILE3;
    const int tid = threadIdx.x;
    const float* __restrict__ cb = cur_in + (size_t)b*Cn*Ln;

    for (int idx = tid; idx < Cn*(TILE3+2); idx += 256) {
        int c = idx / (TILE3+2);
        int j = idx - c*(TILE3+2);
        int l = l0 - 1 + j;
        cur_s[c][j] = (l < 0 || l >= Ln) ? 0.0f : cb[c*Ln + l];
    }
    __syncthreads();

    if (HAS_ATT) {
        for (int i = tid; i < MIDn*TILE3; i += 256) {
            int mm = i / TILE3, t = i - mm*TILE3;
            float a = ab1[mm];
            for (int c = 0; c < Cn; ++c) a = fmaf(aw1[mm*64 + c], cur_s[c][t+1], a);
            t1_s[mm][t] = gelu_f(a);
        }
        __syncthreads();
    }

    const int oc = tid & 63;
    const int pg = tid >> 6;
    const int t0 = pg*16;
    {
        float gv[16];
        const float bb = gb[oc];
        #pragma unroll
        for (int j = 0; j < 16; ++j) gv[j] = bb;
        for (int c = 0; c < Cn; ++c) {
            const float* cr = &cur_s[c][t0];
            const float w0 = gwt[(c*3+0)*64 + oc];
            const float w1 = gwt[(c*3+1)*64 + oc];
            const float w2 = gwt[(c*3+2)*64 + oc];
            float x0 = cr[0], x1 = cr[1];
            #pragma unroll
            for (int j = 0; j < 16; ++j) {
                float x2 = cr[j+2];
                gv[j] = fmaf(w0, x0, fmaf(w1, x1, fmaf(w2, x2, gv[j])));
                x0 = x1; x1 = x2;
            }
        }
        #pragma unroll
        for (int j = 0; j < 16; ++j) gate_s[oc][t0+j] = sigmoid_f(gv[j]);
    }
    if (HAS_ATT) {
        float av[16];
        const float bb = ab2[oc];
        #pragma unroll
        for (int j = 0; j < 16; ++j) av[j] = bb;
        for (int mm = 0; mm < MIDn; ++mm) {
            const float w = aw2t[mm*64 + oc];
            #pragma unroll
            for (int j = 0; j < 16; ++j) av[j] = fmaf(w, t1_s[mm][t0+j], av[j]);
        }
        #pragma unroll
        for (int j = 0; j < 16; ++j) att_s[oc][t0+j] = sigmoid_f(av[j]);
    }
    __syncthreads();

    const size_t gb0 = (size_t)b*Cn*Ln + l0;
    for (int e = tid; e < Cn*TILE3; e += 256) {
        int c = e >> 6, t = e & 63;
        size_t g = gb0 + (size_t)c*Ln + t;
        float d = det[g];
        if (HAS_ATT) { d = d * (1.0f + att_s[c][t]); det[g] = d; }
        cur_out[g] = cur_s[c][t+1] + gate_s[c][t]*d;
    }
}

extern "C" void kernel_launch(void* const* d_in, const int* in_sizes, int n_in,
                              void* d_out, int out_size, void* d_ws, size_t ws_size,
                              hipStream_t stream)
{
    const float* x      = (const float*)d_in[0];
    const float* c1w    = (const float*)d_in[1];
    const float* c1b    = (const float*)d_in[2];
    const float* c2w    = (const float*)d_in[3];
    const float* c2b    = (const float*)d_in[4];
    const float* damp   = (const float*)d_in[5];
    const float* stat_w = (const float*)d_in[6];
    const float* stat_b = (const float*)d_in[7];
    const float* gen1_w = (const float*)d_in[8];
    const float* gen1_b = (const float*)d_in[9];
    const float* gen2_w = (const float*)d_in[10];
    const float* gen2_b = (const float*)d_in[11];
    const float* gate_w = (const float*)d_in[12];
    const float* gate_b = (const float*)d_in[13];
    const float* att_w1 = (const float*)d_in[14];
    const float* att_b1 = (const float*)d_in[15];
    const float* att_w2 = (const float*)d_in[16];
    const float* att_b2 = (const float*)d_in[17];

    float* out = (float*)d_out;
    // workspace: [Z (Nn)] [WSB (Nn)] [gwt 36864][aw2t 2048][m_ws 2048][w1f 12288s][w2f 12288s]
    float* Z    = (float*)d_ws;
    float* WSB  = Z + Nn;
    float* gwt  = WSB + Nn;
    float* aw2t = gwt + 36864;
    float* m_ws = aw2t + 2048;
    bf16_t* w1f = (bf16_t*)(m_ws + 2048);
    bf16_t* w2f = w1f + 12288;

    // RK4 stage states borrow d_out's enhanced slots (free until stage 2)
    float* zA   = out + (size_t)1*Nn;
    float* zB   = out + (size_t)2*Nn;
    float* zC   = out + (size_t)3*Nn;
    float* tail = out + (size_t)4*Nn;

    prep_weights<<<144, 256, 0, stream>>>(c1w, c2w, gate_w, att_w2, w1f, w2f, gwt, aw2t);

    dim3 gOde(Ln/NT, Bn);
    for (int s = 0; s < 10; ++s) {
        const float* z0 = (s == 0) ? x : (const float*)Z;
        ode_mfma<0><<<gOde, 256, 0, stream>>>(z0, z0, z0, z0, zA, w1f, c1b, w2f, c2b, damp);
        ode_mfma<1><<<gOde, 256, 0, stream>>>(zA, z0, z0, z0, zB, w1f, c1b, w2f, c2b, damp);
        ode_mfma<2><<<gOde, 256, 0, stream>>>(zB, z0, z0, z0, zC, w1f, c1b, w2f, c2b, damp);
        ode_mfma<3><<<gOde, 256, 0, stream>>>(zC, z0, zA, zB, Z,  w1f, c1b, w2f, c2b, damp);
    }

    // stage 2: wavelet levels. approx chain: Z -> WSB -> out(cur slot) -> (dropped)
    dim3 gFil(Ln/256, Bn*Cn);
    const float* appr_in[3] = {Z, WSB, out};
    float*       appr_out[3] = {WSB, out, nullptr};
    for (int lvl = 0; lvl < 3; ++lvl) {
        mean_kernel<<<Bn*Cn, 256, 0, stream>>>(appr_in[lvl], m_ws);
        dywan_kernel<<<1, 256, 0, stream>>>(m_ws, stat_w, stat_b, gen1_w, gen1_b,
                                            gen2_w, gen2_b, tail, lvl);
        filter_kernel<<<gFil, 256, 0, stream>>>(appr_in[lvl], appr_out[lvl],
            out + (size_t)(1+lvl)*Nn,
            tail + 1 + lvl*(Bn*FLn),
            tail + 1 + 3*(Bn*FLn) + lvl*(Bn*FLn));
    }

    // stage 3: reconstruction. cur chain: Z -> WSB -> Z -> out (final)
    dim3 gS3(Ln/TILE3, Bn);
    stage3_kernel<false><<<gS3, 256, 0, stream>>>(Z, out + (size_t)3*Nn, WSB,
        gwt + 2*12288, gate_b + 2*64, nullptr, nullptr, nullptr, nullptr);
    stage3_kernel<true><<<gS3, 256, 0, stream>>>(WSB, out + (size_t)2*Nn, Z,
        gwt + 1*12288, gate_b + 1*64, att_w1 + 1024, att_b1 + 16, aw2t + 1024, att_b2 + 64);
    stage3_kernel<true><<<gS3, 256, 0, stream>>>(Z, out + (size_t)1*Nn, out,
        gwt, gate_b, att_w1, att_b1, aw2t, att_b2);
}

// Round 4
// 1596.538 us; speedup vs baseline: 4.7853x; 1.6710x over previous
//
#include <hip/hip_runtime.h>

#define Bn   32
#define Cn   64
#define Ln   4096
#define Nn   (Bn*Cn*Ln)      // 8388608
#define FLn  8
#define MIDn 16
#define TILE3 64
#define NT   128             // ODE output positions per block (tile rows = NT+16)

typedef __bf16 bf16_t;
typedef bf16_t bf16x4 __attribute__((ext_vector_type(4)));
typedef bf16_t bf16x8 __attribute__((ext_vector_type(8)));
typedef float  f32x16 __attribute__((ext_vector_type(16)));

__device__ __forceinline__ float tanh_fast(float x) {
    float ax = fabsf(x);
    float t  = __expf(-2.0f * ax);
    float r  = __fmaf_rn(-2.0f, __fdividef(t, 1.0f + t), 1.0f);
    return copysignf(r, x);
}
__device__ __forceinline__ float gelu_fast(float x) {
    float x3 = x * x * x;
    float u  = 0.7978845608028654f * __fmaf_rn(0.044715f, x3, x);
    return 0.5f * x * (1.0f + tanh_fast(u));
}
__device__ __forceinline__ float sigmoid_f(float x) {
    return 1.0f / (1.0f + __expf(-x));
}

// swizzled LDS element index (pitch 64 bf16 = 128B rows, 8B-granule XOR)
__device__ __forceinline__ int zel(int p, int c) { return p*64 + (c ^ ((p & 15) << 2)); }

// ---------------- weight prep: MFMA A-frags + gate/att transposes ----------------
__global__ __launch_bounds__(256) void prep_weights(
    const float* __restrict__ w1, const float* __restrict__ w2,
    const float* __restrict__ gw, const float* __restrict__ aw2,
    bf16_t* __restrict__ w1f, bf16_t* __restrict__ w2f,
    float* __restrict__ gwt, float* __restrict__ aw2t)
{
    int idx = blockIdx.x*256 + threadIdx.x;
    if (idx < 1536) {
        int lane = idx & 63;
        int f  = (idx >> 6) % 12;
        int mt = (idx >> 6) / 12;
        int tau = f >> 2, ks = f & 3;
        int oc = mt*32 + (lane & 31);
        int c0 = ks*16 + (lane >> 5)*8;
        #pragma unroll
        for (int e = 0; e < 8; ++e) {
            int c = c0 + e;
            w1f[idx*8 + e] = (bf16_t)w1[oc*192 + c*3 + tau];
            w2f[idx*8 + e] = (bf16_t)w2[oc*192 + c*3 + tau];
        }
    }
    if (idx < 3*64*192) {
        int lvl = idx / 12288, rem = idx % 12288;
        int oc = rem / 192, r = rem % 192;
        gwt[lvl*12288 + r*64 + oc] = gw[idx];
    }
    if (idx < 2*64*16) {
        int lvl = idx / 1024, rem = idx % 1024;
        int oc = rem / 16, mm = rem % 16;
        aw2t[lvl*1024 + mm*64 + oc] = aw2[idx];
    }
}

// ---------------- fused full-RK4-step kernel ----------------
// One dispatch = one full RK4 step: 4 f-evals on LDS-resident bf16 state.
// Tile coord p in [0,144): l = l0-8+p. Regions shrink per eval:
//   eval i: h on [2i+1, 143-2i), k on [2i+2, 142-2i); final out p in [8,136).
// Edge semantics: z edge-clamp via ZC row fixups; h[-1]:=h[0], h[L]:=h[L-1]
// via HT row fixups (reference pads the INTERMEDIATE h).
__global__ __launch_bounds__(256, 2) void ode_rk4_step(
    const float* __restrict__ zsrc, float* __restrict__ zdst,
    const bf16_t* __restrict__ w1f, const float* __restrict__ b1,
    const bf16_t* __restrict__ w2f, const float* __restrict__ b2,
    const float* __restrict__ damp_p)
{
    __shared__ bf16_t Z0[144*64];   // step-begin state (read-only after staging)
    __shared__ bf16_t ZC[144*64];   // current eval input / next state
    __shared__ bf16_t HT[144*64];   // h = gelu(conv1(.))

    const int tid  = threadIdx.x;
    const int w    = tid >> 6;
    const int lane = tid & 63;
    const int n31  = lane & 31;
    const int g    = lane >> 5;
    const int mtb  = (w & 1) * 32;              // this wave's oc base
    const int b    = blockIdx.y;
    const int l0   = blockIdx.x * NT;
    const size_t bbase = (size_t)b * Cn * Ln;
    const float damp = damp_p[0];
    const bool blk0 = (blockIdx.x == 0);
    const bool blkE = (blockIdx.x == gridDim.x - 1);

    // ---- stage zsrc -> Z0 and ZC (bf16, transposed, swizzled) ----
    for (int cc = 0; cc < 16; ++cc) {
        int c = (w << 4) + cc;
        const float* zr = zsrc + bbase + (size_t)c * Ln;
        #pragma unroll
        for (int m2 = 0; m2 < 3; ++m2) {
            int p = lane + (m2 << 6);
            if (p < 144) {
                int l = l0 - 8 + p;
                l = l < 0 ? 0 : (l > Ln-1 ? Ln-1 : l);
                bf16_t v = (bf16_t)zr[l];
                Z0[zel(p, c)] = v;
                ZC[zel(p, c)] = v;
            }
        }
    }

    // biases in C-fragment lane order (persist)
    float bias1[16], bias2[16];
    #pragma unroll
    for (int r = 0; r < 16; ++r) {
        int oc = mtb + (r&3) + 8*(r>>2) + 4*g;
        bias1[r] = b1[oc];
        bias2[r] = b2[oc];
    }

    float sum[3][16];   // k1 + 2k2 + 2k3 accumulator, static-indexed only
    #pragma unroll
    for (int it = 0; it < 3; ++it)
        #pragma unroll
        for (int r = 0; r < 16; ++r) sum[it][r] = 0.0f;

    __syncthreads();

    #pragma unroll
    for (int i = 0; i < 4; ++i) {
        const bf16_t* srcZ = (i == 0) ? Z0 : ZC;
        const int hLo = 2*i + 1, hHi = 143 - 2*i;
        const int kLo = 2*i + 2, kHi = 142 - 2*i;

        // ZC edge-clamp fixup (state produced by prev eval): z[l<0]:=z[0], z[l>=L]:=z[L-1]
        if (i > 0) {
            if (blk0 && tid < 64) {
                bf16_t v = ZC[zel(8, tid)];
                #pragma unroll
                for (int r = 0; r < 8; ++r) ZC[zel(r, tid)] = v;
            }
            if (blkE && tid < 64) {
                bf16_t v = ZC[zel(135, tid)];
                #pragma unroll
                for (int r = 136; r < 144; ++r) ZC[zel(r, tid)] = v;
            }
            __syncthreads();
        }

        // ---- phase A: conv1 -> gelu -> HT ----
        {
            bf16x8 af[12];
            const bf16x8* wp = (const bf16x8*)w1f + ((w & 1) * 12) * 64 + lane;
            #pragma unroll
            for (int f = 0; f < 12; ++f) af[f] = wp[f*64];

            #pragma unroll
            for (int it = 0; it < 3; ++it) {
                int u = w + it*4;
                if (u < 10) {
                    int nt = u >> 1;
                    int ph = nt*32 + n31;
                    f32x16 acc = (f32x16)0.0f;
                    #pragma unroll
                    for (int tau = 0; tau < 3; ++tau) {
                        int p = ph + tau - 1;
                        p = p < 0 ? 0 : (p > 143 ? 143 : p);
                        int pr = p*64, sw = (p & 15) << 2;
                        #pragma unroll
                        for (int ks = 0; ks < 4; ++ks) {
                            int c0 = ks*16 + g*8;
                            bf16x4 lo = *(const bf16x4*)&srcZ[pr + ((c0    ) ^ sw)];
                            bf16x4 hi = *(const bf16x4*)&srcZ[pr + ((c0 + 4) ^ sw)];
                            bf16x8 bb = __builtin_shufflevector(lo, hi, 0,1,2,3,4,5,6,7);
                            acc = __builtin_amdgcn_mfma_f32_32x32x16_bf16(af[tau*4+ks], bb, acc, 0, 0, 0);
                        }
                    }
                    if (ph >= hLo && ph < hHi) {
                        int qr = ph*64, qs = (ph & 15) << 2;
                        #pragma unroll
                        for (int t = 0; t < 4; ++t) {
                            bf16x4 hv;
                            #pragma unroll
                            for (int e = 0; e < 4; ++e)
                                hv[e] = (bf16_t)gelu_fast(acc[t*4+e] + bias1[t*4+e]);
                            int oc0 = mtb + t*8 + g*4;
                            *(bf16x4*)&HT[qr + (oc0 ^ qs)] = hv;
                        }
                    }
                }
            }
        }
        __syncthreads();
        // h edge-pad fixup (reference pads h itself)
        if (blk0 && tid < 64) HT[zel(7,   tid)] = HT[zel(8,   tid)];
        if (blkE && tid < 64) HT[zel(136, tid)] = HT[zel(135, tid)];
        __syncthreads();

        // ---- phase B: conv2 -> tanh -> k -> state update / RK4 combine ----
        {
            bf16x8 af[12];
            const bf16x8* wp = (const bf16x8*)w2f + ((w & 1) * 12) * 64 + lane;
            #pragma unroll
            for (int f = 0; f < 12; ++f) af[f] = wp[f*64];

            #pragma unroll
            for (int it = 0; it < 3; ++it) {
                int u = w + it*4;
                if (u < 10) {
                    int nt = u >> 1;
                    int pk = nt*32 + n31;
                    f32x16 acc = (f32x16)0.0f;
                    #pragma unroll
                    for (int tau = 0; tau < 3; ++tau) {
                        int q = pk + tau - 1;
                        q = q < 0 ? 0 : (q > 143 ? 143 : q);
                        int qr = q*64, qs = (q & 15) << 2;
                        #pragma unroll
                        for (int ks = 0; ks < 4; ++ks) {
                            int c0 = ks*16 + g*8;
                            bf16x4 lo = *(const bf16x4*)&HT[qr + ((c0    ) ^ qs)];
                            bf16x4 hi = *(const bf16x4*)&HT[qr + ((c0 + 4) ^ qs)];
                            bf16x8 bb = __builtin_shufflevector(lo, hi, 0,1,2,3,4,5,6,7);
                            acc = __builtin_amdgcn_mfma_f32_32x32x16_bf16(af[tau*4+ks], bb, acc, 0, 0, 0);
                        }
                    }
                    if (pk >= kLo && pk < kHi) {
                        const bool inOut = (pk >= 8 && pk < 136);
                        const int pr = pk*64, sw = (pk & 15) << 2;
                        const int gcol = l0 + pk - 8;
                        #pragma unroll
                        for (int r = 0; r < 16; ++r) {
                            int oc = mtb + (r&3) + 8*(r>>2) + 4*g;
                            int e = pr + (oc ^ sw);
                            float zin_v = (float)srcZ[e];
                            float kv = tanh_fast(acc[r] + bias2[r]) - damp * zin_v;
                            if (i == 0) {
                                ZC[e] = (bf16_t)(zin_v + 0.05f * kv);      // srcZ==Z0
                                if (inOut) sum[it][r] = kv;
                            } else if (i == 1) {
                                ZC[e] = (bf16_t)((float)Z0[e] + 0.05f * kv);
                                if (inOut) sum[it][r] += 2.0f * kv;
                            } else if (i == 2) {
                                ZC[e] = (bf16_t)((float)Z0[e] + 0.10f * kv);
                                if (inOut) sum[it][r] += 2.0f * kv;
                            } else if (inOut) {
                                size_t gof = bbase + (size_t)oc * Ln + gcol;
                                zdst[gof] = zsrc[gof] + (0.1f/6.0f) * (sum[it][r] + kv);
                            }
                        }
                    }
                }
            }
        }
        if (i < 3) __syncthreads();
    }
}

// ---------------- per-row mean over L ----------------
__global__ __launch_bounds__(256) void mean_kernel(const float* __restrict__ in, float* __restrict__ m)
{
    const int bc = blockIdx.x;
    const float* __restrict__ row = in + (size_t)bc*Ln;
    float s = 0.0f;
    for (int l = threadIdx.x; l < Ln; l += 256) s += row[l];
    #pragma unroll
    for (int off = 32; off > 0; off >>= 1) s += __shfl_down(s, off, 64);
    __shared__ float red[4];
    if ((threadIdx.x & 63) == 0) red[threadIdx.x >> 6] = s;
    __syncthreads();
    if (threadIdx.x == 0) m[bc] = (red[0]+red[1]+red[2]+red[3]) * (1.0f/Ln);
}

// ---------------- dywan: tiny MLP -> lo/hi + ortho contribution ----------------
__global__ __launch_bounds__(256) void dywan_kernel(
    const float* __restrict__ m,
    const float* __restrict__ stat_w, const float* __restrict__ stat_b,
    const float* __restrict__ gen1_w, const float* __restrict__ gen1_b,
    const float* __restrict__ gen2_w, const float* __restrict__ gen2_b,
    float* __restrict__ tail, int lvl)
{
    __shared__ float m_s[Bn][Cn];
    __shared__ float stat_s[Bn][64];
    __shared__ float g1_s[Bn][128];
    __shared__ float g_s[Bn][16];
    __shared__ float ored[Bn];
    const int tid = threadIdx.x;
    for (int i = tid; i < Bn*Cn; i += 256) m_s[i>>6][i&63] = m[i];
    __syncthreads();
    for (int i = tid; i < Bn*64; i += 256) {
        int b = i >> 6, h = i & 63;
        float a = stat_b[h];
        for (int c = 0; c < Cn; ++c) a = fmaf(stat_w[h*64+c], m_s[b][c], a);
        stat_s[b][h] = 0.5f * a * (1.0f + erff(a * 0.7071067811865476f));
    }
    __syncthreads();
    for (int i = tid; i < Bn*128; i += 256) {
        int b = i >> 7, j = i & 127;
        float a = gen1_b[j];
        for (int h = 0; h < 64; ++h) a = fmaf(gen1_w[j*64+h], stat_s[b][h], a);
        g1_s[b][j] = 0.5f * a * (1.0f + erff(a * 0.7071067811865476f));
    }
    __syncthreads();
    for (int i = tid; i < Bn*16; i += 256) {
        int b = i >> 4, q = i & 15;
        float a = gen2_b[q];
        for (int j = 0; j < 128; ++j) a = fmaf(gen2_w[q*128+j], g1_s[b][j], a);
        g_s[b][q] = a;
    }
    __syncthreads();
    for (int i = tid; i < Bn*16; i += 256) {
        int b = i >> 4, q = i & 15;
        if (q < FLn) tail[1 + lvl*(Bn*FLn) + b*FLn + q] = g_s[b][q];
        else         tail[1 + 3*(Bn*FLn) + lvl*(Bn*FLn) + b*FLn + (q-FLn)] = g_s[b][q];
    }
    if (tid < Bn) {
        const int b = tid;
        float S1 = 0.f, n2 = 0.f, sm = 0.f, prev = 0.f;
        #pragma unroll
        for (int k = 0; k < FLn; ++k) {
            float v = g_s[b][k];
            S1 += fabsf(v); n2 = fmaf(v, v, n2);
            sm += fabsf(v - prev); prev = v;
        }
        sm += fabsf(prev);
        float den = sqrtf(n2) + 1e-8f;
        float Sn = S1 / den;
        float s2n = n2 / (den*den);
        ored[b] = 0.01f * (3.0f*Sn*Sn*(1.0f/2048.0f) + fabsf(s2n - 1.0f)*(1.0f/32.0f))
                + 0.1f * sm * (1.0f/288.0f);
    }
    __syncthreads();
    if (tid == 0) {
        float o = 0.f;
        for (int b = 0; b < Bn; ++b) o += ored[b];
        if (lvl == 0) tail[0] = o; else tail[0] += o;
    }
}

// ---------------- per-batch 8-tap FIR (lo -> new approx, hi -> details) ----------------
__global__ __launch_bounds__(256) void filter_kernel(
    const float* __restrict__ in, float* __restrict__ napprox,
    float* __restrict__ det,
    const float* __restrict__ lo, const float* __restrict__ hi)
{
    const int bc = blockIdx.y;
    const int b = bc >> 6;
    float lov[8], hiv[8];
    #pragma unroll
    for (int k = 0; k < 8; ++k) { lov[k] = lo[b*8+k]; hiv[k] = hi[b*8+k]; }
    const float* __restrict__ row = in + (size_t)bc*Ln;
    const int l = blockIdx.x*256 + threadIdx.x;
    float na = 0.0f, dv = 0.0f;
    #pragma unroll
    for (int k = 0; k < 8; ++k) {
        int j = l + k - 4;
        j = j < 0 ? 0 : (j >= Ln ? Ln-1 : j);
        float v = row[j];
        na = fmaf(v, lov[k], na);
        dv = fmaf(v, hiv[k], dv);
    }
    size_t g = (size_t)bc*Ln + l;
    if (napprox) napprox[g] = na;
    det[g] = dv;
}

// ---------------- reconstruction: att(1x1) + gate(3-conv, zero pad) + updates ----------------
template<bool HAS_ATT>
__global__ __launch_bounds__(256) void stage3_kernel(
    const float* __restrict__ cur_in, float* __restrict__ det,
    float* __restrict__ cur_out,
    const float* __restrict__ gwt, const float* __restrict__ gb,
    const float* __restrict__ aw1, const float* __restrict__ ab1,
    const float* __restrict__ aw2t, const float* __restrict__ ab2)
{
    __shared__ float cur_s[Cn][TILE3+2];
    __shared__ float t1_s[MIDn][TILE3];
    __shared__ float gate_s[Cn][TILE3+1];   // +1 pad: kill 64-way write conflicts
    __shared__ float att_s[Cn][TILE3+1];
    const int b  = blockIdx.y;
    const int l0 = blockIdx.x * TILE3;
    const int tid = threadIdx.x;
    const float* __restrict__ cb = cur_in + (size_t)b*Cn*Ln;

    for (int idx = tid; idx < Cn*(TILE3+2); idx += 256) {
        int c = idx / (TILE3+2);
        int j = idx - c*(TILE3+2);
        int l = l0 - 1 + j;
        cur_s[c][j] = (l < 0 || l >= Ln) ? 0.0f : cb[c*Ln + l];
    }
    __syncthreads();

    if (HAS_ATT) {
        for (int i = tid; i < MIDn*TILE3; i += 256) {
            int mm = i / TILE3, t = i - mm*TILE3;
            float a = ab1[mm];
            for (int c = 0; c < Cn; ++c) a = fmaf(aw1[mm*64 + c], cur_s[c][t+1], a);
            t1_s[mm][t] = gelu_fast(a);
        }
        __syncthreads();
    }

    const int oc = tid & 63;
    const int pg = tid >> 6;
    const int t0 = pg*16;
    {
        float gv[16];
        const float bb = gb[oc];
        #pragma unroll
        for (int j = 0; j < 16; ++j) gv[j] = bb;
        for (int c8 = 0; c8 < 64; c8 += 8) {
            float wr[24];
            #pragma unroll
            for (int cc = 0; cc < 8; ++cc) {
                wr[cc*3+0] = gwt[((c8+cc)*3+0)*64 + oc];
                wr[cc*3+1] = gwt[((c8+cc)*3+1)*64 + oc];
                wr[cc*3+2] = gwt[((c8+cc)*3+2)*64 + oc];
            }
            #pragma unroll
            for (int cc = 0; cc < 8; ++cc) {
                const float* cr = &cur_s[c8+cc][t0];
                float x0 = cr[0], x1 = cr[1];
                #pragma unroll
                for (int j = 0; j < 16; ++j) {
                    float x2 = cr[j+2];
                    gv[j] = fmaf(wr[cc*3+0], x0, fmaf(wr[cc*3+1], x1, fmaf(wr[cc*3+2], x2, gv[j])));
                    x0 = x1; x1 = x2;
                }
            }
        }
        #pragma unroll
        for (int j = 0; j < 16; ++j) gate_s[oc][t0+j] = sigmoid_f(gv[j]);
    }
    if (HAS_ATT) {
        float av[16];
        float w2r[16];
        #pragma unroll
        for (int mm = 0; mm < MIDn; ++mm) w2r[mm] = aw2t[mm*64 + oc];
        const float bb = ab2[oc];
        #pragma unroll
        for (int j = 0; j < 16; ++j) av[j] = bb;
        #pragma unroll
        for (int mm = 0; mm < MIDn; ++mm) {
            #pragma unroll
            for (int j = 0; j < 16; ++j) av[j] = fmaf(w2r[mm], t1_s[mm][t0+j], av[j]);
        }
        #pragma unroll
        for (int j = 0; j < 16; ++j) att_s[oc][t0+j] = sigmoid_f(av[j]);
    }
    __syncthreads();

    const size_t gb0 = (size_t)b*Cn*Ln + l0;
    for (int e = tid; e < Cn*TILE3; e += 256) {
        int c = e >> 6, t = e & 63;
        size_t g = gb0 + (size_t)c*Ln + t;
        float d = det[g];
        if (HAS_ATT) { d = d * (1.0f + att_s[c][t]); det[g] = d; }
        cur_out[g] = cur_s[c][t+1] + gate_s[c][t]*d;
    }
}

extern "C" void kernel_launch(void* const* d_in, const int* in_sizes, int n_in,
                              void* d_out, int out_size, void* d_ws, size_t ws_size,
                              hipStream_t stream)
{
    const float* x      = (const float*)d_in[0];
    const float* c1w    = (const float*)d_in[1];
    const float* c1b    = (const float*)d_in[2];
    const float* c2w    = (const float*)d_in[3];
    const float* c2b    = (const float*)d_in[4];
    const float* damp   = (const float*)d_in[5];
    const float* stat_w = (const float*)d_in[6];
    const float* stat_b = (const float*)d_in[7];
    const float* gen1_w = (const float*)d_in[8];
    const float* gen1_b = (const float*)d_in[9];
    const float* gen2_w = (const float*)d_in[10];
    const float* gen2_b = (const float*)d_in[11];
    const float* gate_w = (const float*)d_in[12];
    const float* gate_b = (const float*)d_in[13];
    const float* att_w1 = (const float*)d_in[14];
    const float* att_b1 = (const float*)d_in[15];
    const float* att_w2 = (const float*)d_in[16];
    const float* att_b2 = (const float*)d_in[17];

    float* out = (float*)d_out;
    // workspace: [Z (Nn)] [WSB (Nn)] [gwt 36864][aw2t 2048][m_ws 2048][w1f][w2f]
    float* Z    = (float*)d_ws;
    float* WSB  = Z + Nn;
    float* gwt  = WSB + Nn;
    float* aw2t = gwt + 36864;
    float* m_ws = aw2t + 2048;
    bf16_t* w1f = (bf16_t*)(m_ws + 2048);
    bf16_t* w2f = w1f + 12288;

    float* tail = out + (size_t)4*Nn;

    prep_weights<<<144, 256, 0, stream>>>(c1w, c2w, gate_w, att_w2, w1f, w2f, gwt, aw2t);

    // ODE: 10 fused RK4 steps, ping-pong Z <-> WSB, final state in WSB
    dim3 gOde(Ln/NT, Bn);
    for (int s = 0; s < 10; ++s) {
        const float* src = (s == 0) ? x : ((s & 1) ? Z : WSB);
        float*       dst = (s & 1) ? WSB : Z;
        ode_rk4_step<<<gOde, 256, 0, stream>>>(src, dst, w1f, c1b, w2f, c2b, damp);
    }
    // after loop: s=9 (odd) wrote WSB -> x_evolved = WSB, Z free

    // stage 2: wavelet levels. approx chain: WSB -> Z -> out0 -> (dropped)
    dim3 gFil(Ln/256, Bn*Cn);
    const float* appr_in[3]  = {WSB, Z, out};
    float*       appr_out[3] = {Z, out, nullptr};
    for (int lvl = 0; lvl < 3; ++lvl) {
        mean_kernel<<<Bn*Cn, 256, 0, stream>>>(appr_in[lvl], m_ws);
        dywan_kernel<<<1, 256, 0, stream>>>(m_ws, stat_w, stat_b, gen1_w, gen1_b,
                                            gen2_w, gen2_b, tail, lvl);
        filter_kernel<<<gFil, 256, 0, stream>>>(appr_in[lvl], appr_out[lvl],
            out + (size_t)(1+lvl)*Nn,
            tail + 1 + lvl*(Bn*FLn),
            tail + 1 + 3*(Bn*FLn) + lvl*(Bn*FLn));
    }

    // stage 3: reconstruction. cur chain: WSB -> Z -> WSB -> out0 (final)
    dim3 gS3(Ln/TILE3, Bn);
    stage3_kernel<false><<<gS3, 256, 0, stream>>>(WSB, out + (size_t)3*Nn, Z,
        gwt + 2*12288, gate_b + 2*64, nullptr, nullptr, nullptr, nullptr);
    stage3_kernel<true><<<gS3, 256, 0, stream>>>(Z, out + (size_t)2*Nn, WSB,
        gwt + 1*12288, gate_b + 1*64, att_w1 + 1024, att_b1 + 16, aw2t + 1024, att_b2 + 64);
    stage3_kernel<true><<<gS3, 256, 0, stream>>>(WSB, out + (size_t)1*Nn, out,
        gwt, gate_b, att_w1, att_b1, aw2t, att_b2);
}